// Round 20
// baseline (2691.106 us; speedup 1.0000x reference)
//
#include <hip/hip_runtime.h>
#include <hip/hip_bf16.h>
#include <math.h>
#include <stdint.h>

// ViT config
#define VB   32
#define VS   197
#define VD   768
#define VNH  12
#define VDQ  64
#define VL   12
#define VMLP 3072
#define VC   1000
#define VP   256
#define VNPAT 196
#define VTOK (VB * VS)            // 6304
#define TOKD ((size_t)VTOK * VD)  // 4841472 elems

typedef __attribute__((ext_vector_type(4))) float f32x4;
typedef __attribute__((ext_vector_type(8))) short short8;

typedef __attribute__((address_space(1))) const unsigned int GU;
typedef __attribute__((address_space(3))) unsigned int LU;

__device__ __forceinline__ void gload_lds16(const void* g, void* l) {
    __builtin_amdgcn_global_load_lds((GU*)(uintptr_t)g, (LU*)(uintptr_t)l, 16, 0, 0);
}

// T1: bijective XCD-aware block swizzle (m204).
__device__ __forceinline__ void xcd_swz(int gx, int gy, int& bx, int& by) {
    int nwg = gx * gy;
    int hw = by * gx + bx;
    int q = nwg >> 3, r = nwg & 7;
    int xcd = hw & 7, off = hw >> 3;
    int lid = (xcd < r ? xcd * (q + 1) : r * (q + 1) + (xcd - r) * q) + off;
    bx = lid % gx; by = lid / gx;
}

// Fast tanh-form GELU.
__device__ __forceinline__ float gelu_f(float x) {
    float t = 0.7978845608f * x * fmaf(0.044715f, x * x, 1.0f);
    float a = fminf(t * 2.8853900818f, 80.0f);
    float e = __builtin_amdgcn_exp2f(a);
    return x * e * __builtin_amdgcn_rcpf(1.0f + e);
}

__device__ __forceinline__ float bfbits2f(unsigned short v) {
    unsigned u = ((unsigned)v) << 16;
    return __uint_as_float(u);
}

// ---------------------------------------------------------------------------
__global__ void patchify_k(const float* __restrict__ X, __hip_bfloat16* __restrict__ P) {
    int idx = blockIdx.x * 256 + threadIdx.x;
    const int total = VB * VNPAT * VP;
    if (idx >= total) return;
    int i  = idx & 255;
    int p  = (idx >> 8) % VNPAT;
    int b  = (idx >> 8) / VNPAT;
    int pr = p / 14, pc = p % 14;
    int a  = i >> 4, c2 = i & 15;
    P[idx] = __float2bfloat16(X[((size_t)b * 224 + pr * 16 + a) * 224 + pc * 16 + c2]);
}

__global__ void pos_cls_k(float* __restrict__ x, const float* __restrict__ cls) {
    size_t idx = (size_t)blockIdx.x * 256 + threadIdx.x;
    if (idx >= TOKD) return;
    int j = (int)(idx % VD);
    int s = (int)((idx / VD) % VS);
    float jj = (float)(j & ~1);
    float freq = expf(-(jj / (float)VD) * 9.2103403719761836f);
    float ang  = (float)s * freq;
    float pe   = (j & 1) ? cosf(ang) : sinf(ang);
    if (s == 0) x[idx] = cls[j] + pe;
    else        x[idx] += pe;
}

__global__ __launch_bounds__(256) void layernorm_k(
    const float* __restrict__ x, __hip_bfloat16* __restrict__ y,
    const float* __restrict__ g, const float* __restrict__ bta)
{
    int t = blockIdx.x;
    const float* xr = x + (size_t)t * VD;
    __hip_bfloat16* yr = y + (size_t)t * VD;
    int tid = threadIdx.x;
    float v[3];
    float s = 0.f;
    #pragma unroll
    for (int i = 0; i < 3; i++) { v[i] = xr[tid + i * 256]; s += v[i]; }
    __shared__ float red[8];
    #pragma unroll
    for (int off = 32; off; off >>= 1) s += __shfl_xor(s, off);
    int lane = tid & 63, w = tid >> 6;
    if (!lane) red[w] = s;
    __syncthreads();
    float mu = (red[0] + red[1] + red[2] + red[3]) * (1.f / VD);
    float s2 = 0.f;
    #pragma unroll
    for (int i = 0; i < 3; i++) { float d0 = v[i] - mu; s2 += d0 * d0; }
    #pragma unroll
    for (int off = 32; off; off >>= 1) s2 += __shfl_xor(s2, off);
    if (!lane) red[4 + w] = s2;
    __syncthreads();
    float var = (red[4] + red[5] + red[6] + red[7]) * (1.f / VD);
    float rs = rsqrtf(var + 1e-5f);
    #pragma unroll
    for (int i = 0; i < 3; i++) {
        int j = tid + i * 256;
        yr[j] = __float2bfloat16((v[i] - mu) * rs * g[j] + bta[j]);
    }
}

__device__ __forceinline__ unsigned pack2bf(float a, float b) {
    __hip_bfloat16 x = __float2bfloat16(a), y = __float2bfloat16(b);
    unsigned short ux = *(unsigned short*)&x, uy = *(unsigned short*)&y;
    return (unsigned)ux | ((unsigned)uy << 16);
}

// ---------------------------------------------------------------------------
// Fused split-K combine (NPART bf16 partials, stride TOKD) + residual +
// (optional) LayerNorm. 192 threads x 4 contiguous elems, vectorized.
// ---------------------------------------------------------------------------
template<int NPART, int DO_LN>
__global__ __launch_bounds__(192) void combineln_k(
    float* __restrict__ x, const __hip_bfloat16* __restrict__ p,
    const float* __restrict__ bias, const float* __restrict__ g,
    const float* __restrict__ bta, __hip_bfloat16* __restrict__ y)
{
    int t = blockIdx.x;
    size_t base = (size_t)t * VD;
    int tid = threadIdx.x;
    int j0 = tid << 2;
    float4 xv = *(const float4*)&x[base + j0];
    float4 bb = *(const float4*)&bias[j0];
    float v[4] = { xv.x + bb.x, xv.y + bb.y, xv.z + bb.z, xv.w + bb.w };
    #pragma unroll
    for (int np = 0; np < NPART; np++) {
        uint2 u = *(const uint2*)&p[(size_t)np * TOKD + base + j0];
        v[0] += bfbits2f((unsigned short)(u.x & 0xffff));
        v[1] += bfbits2f((unsigned short)(u.x >> 16));
        v[2] += bfbits2f((unsigned short)(u.y & 0xffff));
        v[3] += bfbits2f((unsigned short)(u.y >> 16));
    }
    float4 ov = { v[0], v[1], v[2], v[3] };
    *(float4*)&x[base + j0] = ov;
    if (DO_LN) {
        float s = v[0] + v[1] + v[2] + v[3];
        __shared__ float red[8];
        #pragma unroll
        for (int off = 32; off; off >>= 1) s += __shfl_xor(s, off);
        int lane = tid & 63, w = tid >> 6;     // w in 0..2
        if (!lane) red[w] = s;
        __syncthreads();
        float mu = (red[0] + red[1] + red[2]) * (1.f / VD);
        float s2 = 0.f;
        #pragma unroll
        for (int i = 0; i < 4; i++) { float d0 = v[i] - mu; s2 += d0 * d0; }
        #pragma unroll
        for (int off = 32; off; off >>= 1) s2 += __shfl_xor(s2, off);
        if (!lane) red[4 + w] = s2;
        __syncthreads();
        float var = (red[4] + red[5] + red[6]) * (1.f / VD);
        float rs = rsqrtf(var + 1e-5f);
        float4 gv = *(const float4*)&g[j0];
        float4 bv = *(const float4*)&bta[j0];
        float o0 = (v[0] - mu) * rs * gv.x + bv.x;
        float o1 = (v[1] - mu) * rs * gv.y + bv.y;
        float o2 = (v[2] - mu) * rs * gv.z + bv.z;
        float o3 = (v[3] - mu) * rs * gv.w + bv.w;
        uint2 out;
        out.x = pack2bf(o0, o1);
        out.y = pack2bf(o2, o3);
        *(uint2*)&y[base + j0] = out;
    }
}

__global__ __launch_bounds__(256) void tpose_k(
    const float* __restrict__ in, __hip_bfloat16* __restrict__ out, int R, int C)
{
    __shared__ float t[32][33];
    int c0 = blockIdx.x * 32, r0 = blockIdx.y * 32;
    int tc = threadIdx.x & 31, tr = threadIdx.x >> 5;
    #pragma unroll
    for (int p = 0; p < 4; p++) {
        int r = r0 + tr + p * 8;
        t[tr + p * 8][tc] = (r < R && c0 + tc < C) ? in[(size_t)r * C + c0 + tc] : 0.f;
    }
    __syncthreads();
    #pragma unroll
    for (int p = 0; p < 4; p++) {
        int c = c0 + tr + p * 8;
        if (c < C && r0 + tc < R)
            out[(size_t)c * R + r0 + tc] = __float2bfloat16(t[tc][tr + p * 8]);
    }
}

#define OFF_PROJ (2304 * 768)
#define OFF_M1   (OFF_PROJ + 768 * 768)
#define OFF_M2   (OFF_M1 + 3072 * 768)
#define WT_SH    (OFF_M2 + 768 * 3072)   // 7,077,888 shorts per layer

// ---------------------------------------------------------------------------
// Per-layer weight prep body (shared by wprep_k / wprepall_k).
// ---------------------------------------------------------------------------
__device__ __forceinline__ void wprep_body(
    int z, int tid,
    const float* Wq, const float* Wk, const float* Wv,
    const float* Wp, const float* W1, const float* W2,
    __hip_bfloat16* wT, float t[32][33])
{
    const float* src; __hip_bfloat16* dst;
    int C, ldd, r0, c0;
    if (z < 1728) {
        int head = z / 48, tt = z % 48;
        int m = head / VNH, h = head % VNH;
        src = (m == 0 ? Wq : m == 1 ? Wk : Wv) + (size_t)h * VD * VDQ;
        dst = wT + ((size_t)m * VD + h * VDQ) * VD;
        C = VDQ; ldd = VD;
        r0 = (tt >> 1) * 32; c0 = (tt & 1) * 32;
    } else if (z < 2304) {
        int z2 = z - 1728;
        src = Wp; dst = wT + OFF_PROJ;
        C = VD; ldd = VD;
        r0 = (z2 / 24) * 32; c0 = (z2 % 24) * 32;
    } else if (z < 4608) {
        int z3 = z - 2304;
        src = W1; dst = wT + OFF_M1;
        C = VMLP; ldd = VD;
        r0 = (z3 / 96) * 32; c0 = (z3 % 96) * 32;
    } else {
        int z4 = z - 4608;
        src = W2; dst = wT + OFF_M2;
        C = VD; ldd = VMLP;
        r0 = (z4 / 24) * 32; c0 = (z4 % 24) * 32;
    }
    {
        int r = tid >> 3, cq = (tid & 7) << 2;
        float4 v = *(const float4*)&src[(size_t)(r0 + r) * C + c0 + cq];
        t[r][cq] = v.x; t[r][cq + 1] = v.y; t[r][cq + 2] = v.z; t[r][cq + 3] = v.w;
    }
    __syncthreads();
    {
        int c = tid >> 3, rq = (tid & 7) << 2;
        unsigned u0 = pack2bf(t[rq][c],     t[rq + 1][c]);
        unsigned u1 = pack2bf(t[rq + 2][c], t[rq + 3][c]);
        unsigned* dp = (unsigned*)&dst[(size_t)(c0 + c) * ldd + r0 + rq];
        dp[0] = u0; dp[1] = u1;
    }
}

__global__ __launch_bounds__(256) void wprep_k(
    const float* __restrict__ Wq, const float* __restrict__ Wk,
    const float* __restrict__ Wv, const float* __restrict__ Wp,
    const float* __restrict__ W1, const float* __restrict__ W2,
    __hip_bfloat16* __restrict__ wT)
{
    __shared__ float t[32][33];
    wprep_body(blockIdx.x, threadIdx.x, Wq, Wk, Wv, Wp, W1, W2, wT, t);
}

// All-layer weight prep: one launch, 12 x 6912 blocks -> 12 wT slabs.
__global__ __launch_bounds__(256) void wprepall_k(
    const float* __restrict__ Wq, const float* __restrict__ Wk,
    const float* __restrict__ Wv, const float* __restrict__ Wp,
    const float* __restrict__ W1, const float* __restrict__ W2,
    __hip_bfloat16* __restrict__ wTall)
{
    __shared__ float t[32][33];
    int zg = blockIdx.x;
    int l = zg / 6912, z = zg % 6912;
    const size_t WSZ = (size_t)VNH * VD * VDQ;   // 589824
    wprep_body(z, threadIdx.x,
               Wq + (size_t)l * WSZ, Wk + (size_t)l * WSZ, Wv + (size_t)l * WSZ,
               Wp + (size_t)l * VD * VD,
               W1 + (size_t)l * VD * VMLP,
               W2 + (size_t)l * VMLP * VD,
               wTall + (size_t)l * WT_SH, t);
}

__global__ void cball_k(const float* __restrict__ bq, const float* __restrict__ bk,
                        const float* __restrict__ bv, float* __restrict__ cb) {
    int idx = blockIdx.x * 256 + threadIdx.x;
    if (idx >= VL * 3 * VD) return;
    int l = idx / (3 * VD), n = idx % (3 * VD);
    int m = n / VD, wi = n % VD;
    const float* p = (m == 0) ? bq : (m == 1) ? bk : bv;
    cb[idx] = p[l * VD + wi];
}

__global__ void cls_k(const float* __restrict__ x, __hip_bfloat16* __restrict__ out) {
    int idx = blockIdx.x * 256 + threadIdx.x;
    if (idx >= VB * VD) return;
    int b = idx / VD, d = idx % VD;
    out[idx] = __float2bfloat16(x[(size_t)b * VS * VD + d]);
}

// ---------------------------------------------------------------------------
// bf16 MFMA GEMM (m97-style 128x128) + XCD swizzle — patch/head only.
// ---------------------------------------------------------------------------
template<int EPI>
__global__ __launch_bounds__(256) void bgemm_k(
    const __hip_bfloat16* __restrict__ A,
    const __hip_bfloat16* __restrict__ BT,
    const float* __restrict__ bias,
    void* __restrict__ Co,
    int M, int K, int ldc, int Ncols)
{
    __shared__ short A_s[128][64];
    __shared__ short B_s[128][64];
    int bx = blockIdx.x, by = blockIdx.y;
    xcd_swz(gridDim.x, gridDim.y, bx, by);
    const int tid = threadIdx.x;
    const int w = tid >> 6, l = tid & 63;
    const int row0 = by * 128, col0 = bx * 128;
    const int wm = (w >> 1) << 6, wn = (w & 1) << 6;
    f32x4 acc[4][4] = {};

    const int lr = l >> 3;
    const int sslot = (l & 7) ^ lr;
    int arow[4], brow[4];
    #pragma unroll
    for (int i = 0; i < 4; i++) {
        int r = (4 * w + i) * 8 + lr;
        arow[i] = min(row0 + r, M - 1);
        brow[i] = min(col0 + r, Ncols - 1);
    }
    for (int k0 = 0; k0 < K; k0 += 64) {
        __syncthreads();
        #pragma unroll
        for (int i = 0; i < 4; i++) {
            int ch = 4 * w + i;
            gload_lds16((const void*)(A + (size_t)arow[i] * K + k0 + (sslot << 3)),
                        (void*)(&A_s[ch * 8][0]));
            gload_lds16((const void*)(BT + (size_t)brow[i] * K + k0 + (sslot << 3)),
                        (void*)(&B_s[ch * 8][0]));
        }
        __syncthreads();
        #pragma unroll
        for (int ks = 0; ks < 2; ks++) {
            const int s16 = (ks << 2) + (l >> 4);
            short8 av[4], bv[4];
            #pragma unroll
            for (int i = 0; i < 4; i++) {
                int ar = wm + i * 16 + (l & 15);
                av[i] = *(const short8*)((const char*)&A_s[ar][0] + ((s16 ^ (ar & 7)) << 4));
                int br = wn + i * 16 + (l & 15);
                bv[i] = *(const short8*)((const char*)&B_s[br][0] + ((s16 ^ (br & 7)) << 4));
            }
            #pragma unroll
            for (int i = 0; i < 4; i++)
                #pragma unroll
                for (int j = 0; j < 4; j++)
                    acc[i][j] = __builtin_amdgcn_mfma_f32_16x16x32_bf16(av[i], bv[j], acc[i][j], 0, 0, 0);
        }
    }
    const int rbase = row0 + wm + ((l >> 4) << 2);
    const int cbase = col0 + wn + (l & 15);
    #pragma unroll
    for (int i = 0; i < 4; i++) {
        #pragma unroll
        for (int q = 0; q < 4; q++) {
            int rr = rbase + i * 16 + q;
            if (rr >= M) continue;
            #pragma unroll
            for (int j = 0; j < 4; j++) {
                int c = cbase + j * 16;
                if (c >= Ncols) continue;
                float v = acc[i][j][q] + bias[c];
                if (EPI == 0) {
                    int orow = rr + rr / VNPAT + 1;
                    ((float*)Co)[(size_t)orow * ldc + c] = v;
                } else if (EPI == 1) {
                    ((__hip_bfloat16*)Co)[(size_t)rr * ldc + c] = __float2bfloat16(v);
                } else if (EPI == 2) {
                    ((float*)Co)[(size_t)rr * ldc + c] += v;
                } else if (EPI == 3) {
                    ((__hip_bfloat16*)Co)[(size_t)rr * ldc + c] = __float2bfloat16(gelu_f(v));
                } else {
                    ((float*)Co)[(size_t)rr * ldc + c] = v;
                }
            }
        }
    }
}

// ---------------------------------------------------------------------------
// bgemm10_k: lean 3-ring 128x128 full-K GEMM with bias + epilogue (champion).
// ---------------------------------------------------------------------------
template<int EPI>
__global__ __launch_bounds__(256) void bgemm10_k(
    const __hip_bfloat16* __restrict__ A,
    const __hip_bfloat16* __restrict__ BT,
    const float* __restrict__ bias,
    __hip_bfloat16* __restrict__ Co,
    int M, int K, int ldc)
{
    __shared__ short SA[3][128][32];
    __shared__ short SB[3][128][32];
    int bx = blockIdx.x, by = blockIdx.y;
    xcd_swz(gridDim.x, gridDim.y, bx, by);

    const int tid = threadIdx.x;
    const int w = tid >> 6, l = tid & 63;
    const int fr = l & 15, g = l >> 4;
    const int row0 = by * 128, col0 = bx * 128;
    const int wm = (w >> 1) << 6, wn = (w & 1) << 6;
    f32x4 acc[4][4] = {};

    const __hip_bfloat16* aS[2]; const __hip_bfloat16* bS[2];
    int doff[2];
    #pragma unroll
    for (int q = 0; q < 2; q++) {
        int idx = tid + (q << 8);
        int r = idx >> 2;
        int s = (idx & 3) ^ ((r >> 1) & 3);
        aS[q] = A  + (size_t)min(row0 + r, M - 1) * K + s * 8;
        bS[q] = BT + (size_t)(col0 + r) * K + s * 8;
        doff[q] = idx << 4;
    }

    #define STG10(ring, t) { const int k0 = (t) << 5;                          \
        gload_lds16(aS[0] + k0, (char*)&SA[ring][0][0] + doff[0]);             \
        gload_lds16(aS[1] + k0, (char*)&SA[ring][0][0] + doff[1]);             \
        gload_lds16(bS[0] + k0, (char*)&SB[ring][0][0] + doff[0]);             \
        gload_lds16(bS[1] + k0, (char*)&SB[ring][0][0] + doff[1]); }

    const int nt = K >> 5;
    STG10(0, 0);
    STG10(1, 1);
    asm volatile("s_waitcnt vmcnt(4)" ::: "memory");
    __builtin_amdgcn_s_barrier();

    for (int t = 0; t < nt; t++) {
        const int ring = t % 3;
        const int rs   = (t + 2) % 3;
        const char* sa = (const char*)&SA[ring][0][0];
        const char* sb = (const char*)&SB[ring][0][0];
        short8 av[4], bv[4];
        #pragma unroll
        for (int i = 0; i < 4; i++) {
            int ar = wm + i * 16 + fr;
            av[i] = *(const short8*)(sa + ar * 64 + ((g ^ ((ar >> 1) & 3)) << 4));
            int br = wn + i * 16 + fr;
            bv[i] = *(const short8*)(sb + br * 64 + ((g ^ ((br >> 1) & 3)) << 4));
        }
        if (t + 2 < nt) STG10(rs, t + 2);
        asm volatile("s_waitcnt lgkmcnt(0)" ::: "memory");
        __builtin_amdgcn_sched_barrier(0);
        __builtin_amdgcn_s_setprio(1);
        #pragma unroll
        for (int i = 0; i < 4; i++)
            #pragma unroll
            for (int j = 0; j < 4; j++)
                acc[i][j] = __builtin_amdgcn_mfma_f32_16x16x32_bf16(av[i], bv[j], acc[i][j], 0, 0, 0);
        __builtin_amdgcn_s_setprio(0);
        if (t + 2 < nt) {
            asm volatile("s_waitcnt vmcnt(4)" ::: "memory");
            __builtin_amdgcn_s_barrier();
        } else if (t + 1 < nt) {
            asm volatile("s_waitcnt vmcnt(0)" ::: "memory");
            __builtin_amdgcn_s_barrier();
        }
    }
    #undef STG10

    const int rbase = row0 + wm + (g << 2);
    const int cbase = col0 + wn + fr;
    #pragma unroll
    for (int i = 0; i < 4; i++) {
        #pragma unroll
        for (int q = 0; q < 4; q++) {
            int rr = rbase + i * 16 + q;
            if (rr >= M) continue;
            #pragma unroll
            for (int j = 0; j < 4; j++) {
                int c = cbase + j * 16;
                float v = acc[i][j][q] + bias[c];
                if (EPI == 3) v = gelu_f(v);
                Co[(size_t)rr * ldc + c] = __float2bfloat16(v);
            }
        }
    }
}

// ---------------------------------------------------------------------------
// bgemm9_k<NSPLIT>: split-K partial GEMM, lean 3-ring 128x128, bf16 partials.
// ---------------------------------------------------------------------------
template<int NSPLIT>
__global__ __launch_bounds__(256) void bgemm9_k(
    const __hip_bfloat16* __restrict__ A,
    const __hip_bfloat16* __restrict__ BT,
    __hip_bfloat16* __restrict__ P,
    int M, int K, int ldc)
{
    __shared__ short SA[3][128][32];
    __shared__ short SB[3][128][32];
    int bx = blockIdx.x, by = blockIdx.y;
    xcd_swz(gridDim.x, gridDim.y, bx, by);
    const int ks = blockIdx.z;
    const int kpart = K / NSPLIT;
    const __hip_bfloat16* Ab  = A  + (size_t)ks * kpart;
    const __hip_bfloat16* BTb = BT + (size_t)ks * kpart;
    __hip_bfloat16* Pb = P + (size_t)ks * TOKD;

    const int tid = threadIdx.x;
    const int w = tid >> 6, l = tid & 63;
    const int fr = l & 15, g = l >> 4;
    const int row0 = by * 128, col0 = bx * 128;
    const int wm = (w >> 1) << 6, wn = (w & 1) << 6;
    f32x4 acc[4][4] = {};

    const __hip_bfloat16* aS[2]; const __hip_bfloat16* bS[2];
    int doff[2];
    #pragma unroll
    for (int q = 0; q < 2; q++) {
        int idx = tid + (q << 8);
        int r = idx >> 2;
        int s = (idx & 3) ^ ((r >> 1) & 3);
        aS[q] = Ab  + (size_t)min(row0 + r, M - 1) * K + s * 8;
        bS[q] = BTb + (size_t)(col0 + r) * K + s * 8;
        doff[q] = idx << 4;
    }

    #define STG9(ring, t) { const int k0 = (t) << 5;                           \
        gload_lds16(aS[0] + k0, (char*)&SA[ring][0][0] + doff[0]);             \
        gload_lds16(aS[1] + k0, (char*)&SA[ring][0][0] + doff[1]);             \
        gload_lds16(bS[0] + k0, (char*)&SB[ring][0][0] + doff[0]);             \
        gload_lds16(bS[1] + k0, (char*)&SB[ring][0][0] + doff[1]); }

    const int nt = kpart >> 5;
    STG9(0, 0);
    STG9(1, 1);
    asm volatile("s_waitcnt vmcnt(4)" ::: "memory");
    __builtin_amdgcn_s_barrier();

    for (int t = 0; t < nt; t++) {
        const int ring = t % 3;
        const int rs   = (t + 2) % 3;
        const char* sa = (const char*)&SA[ring][0][0];
        const char* sb = (const char*)&SB[ring][0][0];
        short8 av[4], bv[4];
        #pragma unroll
        for (int i = 0; i < 4; i++) {
            int ar = wm + i * 16 + fr;
            av[i] = *(const short8*)(sa + ar * 64 + ((g ^ ((ar >> 1) & 3)) << 4));
            int br = wn + i * 16 + fr;
            bv[i] = *(const short8*)(sb + br * 64 + ((g ^ ((br >> 1) & 3)) << 4));
        }
        if (t + 2 < nt) STG9(rs, t + 2);
        asm volatile("s_waitcnt lgkmcnt(0)" ::: "memory");
        __builtin_amdgcn_sched_barrier(0);
        __builtin_amdgcn_s_setprio(1);
        #pragma unroll
        for (int i = 0; i < 4; i++)
            #pragma unroll
            for (int j = 0; j < 4; j++)
                acc[i][j] = __builtin_amdgcn_mfma_f32_16x16x32_bf16(av[i], bv[j], acc[i][j], 0, 0, 0);
        __builtin_amdgcn_s_setprio(0);
        if (t + 2 < nt) {
            asm volatile("s_waitcnt vmcnt(4)" ::: "memory");
            __builtin_amdgcn_s_barrier();
        } else if (t + 1 < nt) {
            asm volatile("s_waitcnt vmcnt(0)" ::: "memory");
            __builtin_amdgcn_s_barrier();
        }
    }
    #undef STG9

    const int rbase = row0 + wm + (g << 2);
    const int cbase = col0 + wn + fr;
    #pragma unroll
    for (int i = 0; i < 4; i++) {
        #pragma unroll
        for (int q = 0; q < 4; q++) {
            int rr = rbase + i * 16 + q;
            if (rr >= M) continue;
            #pragma unroll
            for (int j = 0; j < 4; j++) {
                int c = cbase + j * 16;
                Pb[(size_t)rr * ldc + c] = __float2bfloat16(acc[i][j][q]);
            }
        }
    }
}

// ---------------------------------------------------------------------------
// MFMA attention. Two blocks per (b,h), 256 threads, 4 waves.
// ---------------------------------------------------------------------------
__device__ __forceinline__ int swz_idx(int row, int k) {
    return row * 256 + (((k >> 3) ^ (row & 7)) << 3) + (k & 7);
}

__global__ __launch_bounds__(256) void attn3_k(
    const __hip_bfloat16* __restrict__ qkv, __hip_bfloat16* __restrict__ o)
{
    __shared__ short V_t[64 * 256];
    __shared__ short P_s[4][16 * 256];
    const int half = blockIdx.x;
    const int bh = blockIdx.y;
    const int b = bh / VNH, h = bh % VNH;
    const int tid = threadIdx.x, w = tid >> 6, l = tid & 63;
    const int g = l >> 4, c16 = l & 15;

    const __hip_bfloat16* base = qkv + (size_t)(b * VS) * (3 * VD) + h * VDQ;

    {
        const __hip_bfloat16* vbase = base + 2 * VD;
        int t = tid & 31, e0 = (tid >> 5) * 8;
        #pragma unroll
        for (int it = 0; it < 7; it++) {
            int tt = it * 32 + t;
            if (tt < VS) {
                short8 vv = *(const short8*)(vbase + (size_t)tt * (3 * VD) + e0);
                #pragma unroll
                for (int j = 0; j < 8; j++) V_t[swz_idx(e0 + j, tt)] = vv[j];
            }
        }
        for (int idx = tid; idx < 64 * 27; idx += 256) {
            int e = idx / 27, k = 197 + idx % 27;
            V_t[swz_idx(e, k)] = 0;
        }
    }
    {
        unsigned* p0 = (unsigned*)&P_s[w][swz_idx(c16, 208 + g * 4)];
        p0[0] = 0; p0[1] = 0;
    }
    __syncthreads();

    const int qt_end = half ? 13 : 7;
    for (int qt = 7 * half + w; qt < qt_end; qt += 4) {
        const int q0 = qt * 16;
        int qr = min(q0 + c16, VS - 1);
        const __hip_bfloat16* qp = base + (size_t)qr * (3 * VD) + g * 8;
        short8 qa0 = *(const short8*)(qp);
        short8 qa1 = *(const short8*)(qp + 32);

        f32x4 st[13];
        __builtin_amdgcn_s_setprio(1);
        #pragma unroll
        for (int t = 0; t < 13; t++) {
            int kr = min(t * 16 + c16, VS - 1);
            const __hip_bfloat16* kp = base + VD + (size_t)kr * (3 * VD) + g * 8;
            short8 ka0 = *(const short8*)(kp);
            short8 ka1 = *(const short8*)(kp + 32);
            f32x4 z = {};
            z = __builtin_amdgcn_mfma_f32_16x16x32_bf16(ka0, qa0, z, 0, 0, 0);
            z = __builtin_amdgcn_mfma_f32_16x16x32_bf16(ka1, qa1, z, 0, 0, 0);
            st[t] = z;
        }
        __builtin_amdgcn_s_setprio(0);
        #pragma unroll
        for (int t = 0; t < 13; t++) {
            #pragma unroll
            for (int r = 0; r < 4; r++) {
                float v = st[t][r] * 0.125f;
                if (t == 12 && (4 * g + r) >= 5) v = -3.0e38f;
                st[t][r] = v;
            }
        }
        float m = -3.0e38f;
        #pragma unroll
        for (int t = 0; t < 13; t++)
            #pragma unroll
            for (int r = 0; r < 4; r++) m = fmaxf(m, st[t][r]);
        m = fmaxf(m, __shfl_xor(m, 16));
        m = fmaxf(m, __shfl_xor(m, 32));
        float sum = 0.f;
        #pragma unroll
        for (int t = 0; t < 13; t++)
            #pragma unroll
            for (int r = 0; r < 4; r++) { float e = expf(st[t][r] - m); st[t][r] = e; sum += e; }
        sum += __shfl_xor(sum, 16);
        sum += __shfl_xor(sum, 32);
        float inv = 1.f / sum;
        #pragma unroll
        for (int t = 0; t < 13; t++) {
            int k0 = 16 * t + 4 * g;
            unsigned* pp = (unsigned*)&P_s[w][swz_idx(c16, k0)];
            pp[0] = pack2bf(st[t][0] * inv, st[t][1] * inv);
            pp[1] = pack2bf(st[t][2] * inv, st[t][3] * inv);
        }
        f32x4 acc[4] = {};
        __builtin_amdgcn_s_setprio(1);
        #pragma unroll
        for (int ki = 0; ki < 7; ki++) {
            int k0 = ki * 32 + g * 8;
            short8 pa = *(const short8*)&P_s[w][swz_idx(c16, k0)];
            #pragma unroll
            for (int et = 0; et < 4; et++) {
                short8 vbf = *(const short8*)&V_t[swz_idx(et * 16 + c16, k0)];
                acc[et] = __builtin_amdgcn_mfma_f32_16x16x32_bf16(pa, vbf, acc[et], 0, 0, 0);
            }
        }
        __builtin_amdgcn_s_setprio(0);
        #pragma unroll
        for (int et = 0; et < 4; et++) {
            #pragma unroll
            for (int r = 0; r < 4; r++) {
                int q = q0 + 4 * g + r;
                if (q < VS)
                    o[((size_t)(b * VS) + q) * VD + h * VDQ + et * 16 + c16] =
                        __float2bfloat16(acc[et][r]);
            }
        }
    }
}

// ---------------------------------------------------------------------------
extern "C" void kernel_launch(void* const* d_in, const int* in_sizes, int n_in,
                              void* d_out, int out_size, void* d_ws, size_t ws_size,
                              hipStream_t stream) {
    (void)in_sizes; (void)n_in; (void)out_size;
    const float* X       = (const float*)d_in[0];
    const float* patch_W = (const float*)d_in[1];
    const float* patch_b = (const float*)d_in[2];
    const float* cls_tok = (const float*)d_in[3];
    const float* ln1_g   = (const float*)d_in[4];
    const float* ln1_b   = (const float*)d_in[5];
    const float* Wq      = (const float*)d_in[6];
    const float* bq      = (const float*)d_in[7];
    const float* Wk      = (const float*)d_in[8];
    const float* bk      = (const float*)d_in[9];
    const float* Wv      = (const float*)d_in[10];
    const float* bv      = (const float*)d_in[11];
    const float* proj_W  = (const float*)d_in[12];
    const float* proj_b  = (const float*)d_in[13];
    const float* ln2_g   = (const float*)d_in[14];
    const float* ln2_b   = (const float*)d_in[15];
    const float* mlp_W1  = (const float*)d_in[16];
    const float* mlp_b1  = (const float*)d_in[17];
    const float* mlp_W2  = (const float*)d_in[18];
    const float* mlp_b2  = (const float*)d_in[19];
    const float* head_W  = (const float*)d_in[20];
    const float* head_b  = (const float*)d_in[21];

    char* ws = (char*)d_ws;
    float*          x    = (float*)ws;                            // 19.37 MB fp32
    __hip_bfloat16* tb   = (__hip_bfloat16*)(ws + 19365888);      // 9.68 MB bf16
    __hip_bfloat16* big  = (__hip_bfloat16*)(ws + 29048832);      // 38.73 MB
    __hip_bfloat16* wT   = (__hip_bfloat16*)(ws + 67780608);      // 14.16 MB
    float*          cbA  = (float*)(ws + 81936384);               // 110 KB
    __hip_bfloat16* pbuf = (__hip_bfloat16*)(ws + 82046976);      // 38.73 MB (4x TOKD bf16)
    // Optional hoisted all-layer weight slab (12 x 14.16 MB) after pbuf.
    __hip_bfloat16* wTall = (__hip_bfloat16*)(ws + 120778752);
    const int hoist = (ws_size >= 120778752ULL + (size_t)12 * WT_SH * 2) ? 1 : 0;

    cball_k<<<(VL * 3 * VD + 255) / 256, 256, 0, stream>>>(bq, bk, bv, cbA);

    if (hoist)
        wprepall_k<<<12 * 6912, 256, 0, stream>>>(Wq, Wk, Wv, proj_W,
                                                  mlp_W1, mlp_W2, wTall);

    patchify_k<<<(VB * VNPAT * VP + 255) / 256, 256, 0, stream>>>(X, big);
    {
        dim3 g(VD / 32, VP / 32);
        tpose_k<<<g, 256, 0, stream>>>(patch_W, wT, VP, VD);
    }
    {
        dim3 g(VD / 128, VB * VNPAT / 128);
        bgemm_k<0><<<g, 256, 0, stream>>>(big, wT, patch_b, x, VB * VNPAT, VP, VD, VD);
    }
    pos_cls_k<<<(unsigned)((TOKD + 255) / 256), 256, 0, stream>>>(x, cls_tok);

    const size_t WSZ = (size_t)VNH * VD * VDQ;
    for (int l = 0; l < VL; l++) {
        __hip_bfloat16* wTl;
        if (hoist) {
            wTl = wTall + (size_t)l * WT_SH;
        } else {
            wprep_k<<<6912, 256, 0, stream>>>(
                Wq + l * WSZ, Wk + l * WSZ, Wv + l * WSZ,
                proj_W + (size_t)l * VD * VD,
                mlp_W1 + (size_t)l * VD * VMLP,
                mlp_W2 + (size_t)l * VMLP * VD, wT);
            wTl = wT;
        }

        if (l == 0)
            layernorm_k<<<VTOK, 256, 0, stream>>>(x, tb, ln1_g, ln1_b);

        {
            // fused QKV GEMM: lean 128² 3-ring, grid 18 x 50
            dim3 g(3 * VD / 128, (VTOK + 127) / 128);
            bgemm10_k<1><<<g, 256, 0, stream>>>(tb, wTl, cbA + l * 3 * VD, big,
                                                VTOK, VD, 3 * VD);
        }
        {
            dim3 ga(2, VB * VNH);
            attn3_k<<<ga, 256, 0, stream>>>(big, tb);
        }
        {
            // proj split-K=2 (bf16 partials), then combine + residual + LN2
            dim3 g(VD / 128, (VTOK + 127) / 128, 2);
            bgemm9_k<2><<<g, 256, 0, stream>>>(tb, wTl + OFF_PROJ, pbuf, VTOK, VD, VD);
            combineln_k<2, 1><<<VTOK, 192, 0, stream>>>(
                x, pbuf, proj_b + l * VD,
                ln2_g + l * VD, ln2_b + l * VD, tb);
        }
        {
            // MLP1: lean 128² 3-ring + fast-GELU, grid 24 x 50
            dim3 g(VMLP / 128, (VTOK + 127) / 128);
            bgemm10_k<3><<<g, 256, 0, stream>>>(tb, wTl + OFF_M1, mlp_b1 + l * VMLP, big,
                                                VTOK, VD, VMLP);
        }
        {
            // MLP2 split-K=4 (bf16 partials), then combine(4) + residual (+ next LN1)
            dim3 g(VD / 128, (VTOK + 127) / 128, 4);
            bgemm9_k<4><<<g, 256, 0, stream>>>(big, wTl + OFF_M2, pbuf, VTOK, VMLP, VD);
            if (l + 1 < VL)
                combineln_k<4, 1><<<VTOK, 192, 0, stream>>>(
                    x, pbuf, mlp_b2 + l * VD,
                    ln1_g + (l + 1) * VD, ln1_b + (l + 1) * VD, tb);
            else
                combineln_k<4, 0><<<VTOK, 192, 0, stream>>>(
                    x, pbuf, mlp_b2 + l * VD,
                    nullptr, nullptr, nullptr);
        }
    }
    cls_k<<<(VB * VD + 255) / 256, 256, 0, stream>>>(x, tb);
    {
        dim3 gt((VC + 31) / 32, VD / 32);
        tpose_k<<<gt, 256, 0, stream>>>(head_W, wT, VD, VC);
        dim3 g((VC + 127) / 128, 1);
        bgemm_k<4><<<g, 256, 0, stream>>>(tb, wT, head_b, (float*)d_out,
                                          VB, VD, VC, VC);
    }
}

// Round 21
// 2644.256 us; speedup vs baseline: 1.0177x; 1.0177x over previous
//
#include <hip/hip_runtime.h>
#include <hip/hip_bf16.h>
#include <math.h>
#include <stdint.h>

// ViT config
#define VB   32
#define VS   197
#define VD   768
#define VNH  12
#define VDQ  64
#define VL   12
#define VMLP 3072
#define VC   1000
#define VP   256
#define VNPAT 196
#define VTOK (VB * VS)            // 6304
#define TOKD ((size_t)VTOK * VD)  // 4841472 elems

typedef __attribute__((ext_vector_type(4))) float f32x4;
typedef __attribute__((ext_vector_type(8))) short short8;

typedef __attribute__((address_space(1))) const unsigned int GU;
typedef __attribute__((address_space(3))) unsigned int LU;

__device__ __forceinline__ void gload_lds16(const void* g, void* l) {
    __builtin_amdgcn_global_load_lds((GU*)(uintptr_t)g, (LU*)(uintptr_t)l, 16, 0, 0);
}

// T1: bijective XCD-aware block swizzle (m204).
__device__ __forceinline__ void xcd_swz(int gx, int gy, int& bx, int& by) {
    int nwg = gx * gy;
    int hw = by * gx + bx;
    int q = nwg >> 3, r = nwg & 7;
    int xcd = hw & 7, off = hw >> 3;
    int lid = (xcd < r ? xcd * (q + 1) : r * (q + 1) + (xcd - r) * q) + off;
    bx = lid % gx; by = lid / gx;
}

// Fast tanh-form GELU.
__device__ __forceinline__ float gelu_f(float x) {
    float t = 0.7978845608f * x * fmaf(0.044715f, x * x, 1.0f);
    float a = fminf(t * 2.8853900818f, 80.0f);
    float e = __builtin_amdgcn_exp2f(a);
    return x * e * __builtin_amdgcn_rcpf(1.0f + e);
}

__device__ __forceinline__ float bfbits2f(unsigned short v) {
    unsigned u = ((unsigned)v) << 16;
    return __uint_as_float(u);
}

// ---------------------------------------------------------------------------
__global__ void patchify_k(const float* __restrict__ X, __hip_bfloat16* __restrict__ P) {
    int idx = blockIdx.x * 256 + threadIdx.x;
    const int total = VB * VNPAT * VP;
    if (idx >= total) return;
    int i  = idx & 255;
    int p  = (idx >> 8) % VNPAT;
    int b  = (idx >> 8) / VNPAT;
    int pr = p / 14, pc = p % 14;
    int a  = i >> 4, c2 = i & 15;
    P[idx] = __float2bfloat16(X[((size_t)b * 224 + pr * 16 + a) * 224 + pc * 16 + c2]);
}

__global__ void pos_cls_k(float* __restrict__ x, const float* __restrict__ cls) {
    size_t idx = (size_t)blockIdx.x * 256 + threadIdx.x;
    if (idx >= TOKD) return;
    int j = (int)(idx % VD);
    int s = (int)((idx / VD) % VS);
    float jj = (float)(j & ~1);
    float freq = expf(-(jj / (float)VD) * 9.2103403719761836f);
    float ang  = (float)s * freq;
    float pe   = (j & 1) ? cosf(ang) : sinf(ang);
    if (s == 0) x[idx] = cls[j] + pe;
    else        x[idx] += pe;
}

__global__ __launch_bounds__(256) void layernorm_k(
    const float* __restrict__ x, __hip_bfloat16* __restrict__ y,
    const float* __restrict__ g, const float* __restrict__ bta)
{
    int t = blockIdx.x;
    const float* xr = x + (size_t)t * VD;
    __hip_bfloat16* yr = y + (size_t)t * VD;
    int tid = threadIdx.x;
    float v[3];
    float s = 0.f;
    #pragma unroll
    for (int i = 0; i < 3; i++) { v[i] = xr[tid + i * 256]; s += v[i]; }
    __shared__ float red[8];
    #pragma unroll
    for (int off = 32; off; off >>= 1) s += __shfl_xor(s, off);
    int lane = tid & 63, w = tid >> 6;
    if (!lane) red[w] = s;
    __syncthreads();
    float mu = (red[0] + red[1] + red[2] + red[3]) * (1.f / VD);
    float s2 = 0.f;
    #pragma unroll
    for (int i = 0; i < 3; i++) { float d0 = v[i] - mu; s2 += d0 * d0; }
    #pragma unroll
    for (int off = 32; off; off >>= 1) s2 += __shfl_xor(s2, off);
    if (!lane) red[4 + w] = s2;
    __syncthreads();
    float var = (red[4] + red[5] + red[6] + red[7]) * (1.f / VD);
    float rs = rsqrtf(var + 1e-5f);
    #pragma unroll
    for (int i = 0; i < 3; i++) {
        int j = tid + i * 256;
        yr[j] = __float2bfloat16((v[i] - mu) * rs * g[j] + bta[j]);
    }
}

__device__ __forceinline__ unsigned pack2bf(float a, float b) {
    __hip_bfloat16 x = __float2bfloat16(a), y = __float2bfloat16(b);
    unsigned short ux = *(unsigned short*)&x, uy = *(unsigned short*)&y;
    return (unsigned)ux | ((unsigned)uy << 16);
}

// ---------------------------------------------------------------------------
// Fused split-K combine (NPART bf16 partials, stride TOKD) + residual +
// (optional) LayerNorm. 192 threads x 4 contiguous elems, vectorized.
// ---------------------------------------------------------------------------
template<int NPART, int DO_LN>
__global__ __launch_bounds__(192) void combineln_k(
    float* __restrict__ x, const __hip_bfloat16* __restrict__ p,
    const float* __restrict__ bias, const float* __restrict__ g,
    const float* __restrict__ bta, __hip_bfloat16* __restrict__ y)
{
    int t = blockIdx.x;
    size_t base = (size_t)t * VD;
    int tid = threadIdx.x;
    int j0 = tid << 2;
    float4 xv = *(const float4*)&x[base + j0];
    float4 bb = *(const float4*)&bias[j0];
    float v[4] = { xv.x + bb.x, xv.y + bb.y, xv.z + bb.z, xv.w + bb.w };
    #pragma unroll
    for (int np = 0; np < NPART; np++) {
        uint2 u = *(const uint2*)&p[(size_t)np * TOKD + base + j0];
        v[0] += bfbits2f((unsigned short)(u.x & 0xffff));
        v[1] += bfbits2f((unsigned short)(u.x >> 16));
        v[2] += bfbits2f((unsigned short)(u.y & 0xffff));
        v[3] += bfbits2f((unsigned short)(u.y >> 16));
    }
    float4 ov = { v[0], v[1], v[2], v[3] };
    *(float4*)&x[base + j0] = ov;
    if (DO_LN) {
        float s = v[0] + v[1] + v[2] + v[3];
        __shared__ float red[8];
        #pragma unroll
        for (int off = 32; off; off >>= 1) s += __shfl_xor(s, off);
        int lane = tid & 63, w = tid >> 6;     // w in 0..2
        if (!lane) red[w] = s;
        __syncthreads();
        float mu = (red[0] + red[1] + red[2]) * (1.f / VD);
        float s2 = 0.f;
        #pragma unroll
        for (int i = 0; i < 4; i++) { float d0 = v[i] - mu; s2 += d0 * d0; }
        #pragma unroll
        for (int off = 32; off; off >>= 1) s2 += __shfl_xor(s2, off);
        if (!lane) red[4 + w] = s2;
        __syncthreads();
        float var = (red[4] + red[5] + red[6]) * (1.f / VD);
        float rs = rsqrtf(var + 1e-5f);
        float4 gv = *(const float4*)&g[j0];
        float4 bv = *(const float4*)&bta[j0];
        float o0 = (v[0] - mu) * rs * gv.x + bv.x;
        float o1 = (v[1] - mu) * rs * gv.y + bv.y;
        float o2 = (v[2] - mu) * rs * gv.z + bv.z;
        float o3 = (v[3] - mu) * rs * gv.w + bv.w;
        uint2 out;
        out.x = pack2bf(o0, o1);
        out.y = pack2bf(o2, o3);
        *(uint2*)&y[base + j0] = out;
    }
}

__global__ __launch_bounds__(256) void tpose_k(
    const float* __restrict__ in, __hip_bfloat16* __restrict__ out, int R, int C)
{
    __shared__ float t[32][33];
    int c0 = blockIdx.x * 32, r0 = blockIdx.y * 32;
    int tc = threadIdx.x & 31, tr = threadIdx.x >> 5;
    #pragma unroll
    for (int p = 0; p < 4; p++) {
        int r = r0 + tr + p * 8;
        t[tr + p * 8][tc] = (r < R && c0 + tc < C) ? in[(size_t)r * C + c0 + tc] : 0.f;
    }
    __syncthreads();
    #pragma unroll
    for (int p = 0; p < 4; p++) {
        int c = c0 + tr + p * 8;
        if (c < C && r0 + tc < R)
            out[(size_t)c * R + r0 + tc] = __float2bfloat16(t[tc][tr + p * 8]);
    }
}

#define OFF_PROJ (2304 * 768)
#define OFF_M1   (OFF_PROJ + 768 * 768)
#define OFF_M2   (OFF_M1 + 3072 * 768)

__global__ __launch_bounds__(256) void wprep_k(
    const float* __restrict__ Wq, const float* __restrict__ Wk,
    const float* __restrict__ Wv, const float* __restrict__ Wp,
    const float* __restrict__ W1, const float* __restrict__ W2,
    __hip_bfloat16* __restrict__ wT)
{
    __shared__ float t[32][33];
    int z = blockIdx.x;
    const float* src; __hip_bfloat16* dst;
    int C, ldd, r0, c0;
    if (z < 1728) {
        int head = z / 48, tt = z % 48;
        int m = head / VNH, h = head % VNH;
        src = (m == 0 ? Wq : m == 1 ? Wk : Wv) + (size_t)h * VD * VDQ;
        dst = wT + ((size_t)m * VD + h * VDQ) * VD;
        C = VDQ; ldd = VD;
        r0 = (tt >> 1) * 32; c0 = (tt & 1) * 32;
    } else if (z < 2304) {
        int z2 = z - 1728;
        src = Wp; dst = wT + OFF_PROJ;
        C = VD; ldd = VD;
        r0 = (z2 / 24) * 32; c0 = (z2 % 24) * 32;
    } else if (z < 4608) {
        int z3 = z - 2304;
        src = W1; dst = wT + OFF_M1;
        C = VMLP; ldd = VD;
        r0 = (z3 / 96) * 32; c0 = (z3 % 96) * 32;
    } else {
        int z4 = z - 4608;
        src = W2; dst = wT + OFF_M2;
        C = VD; ldd = VMLP;
        r0 = (z4 / 24) * 32; c0 = (z4 % 24) * 32;
    }
    int tid = threadIdx.x;
    {
        int r = tid >> 3, cq = (tid & 7) << 2;
        float4 v = *(const float4*)&src[(size_t)(r0 + r) * C + c0 + cq];
        t[r][cq] = v.x; t[r][cq + 1] = v.y; t[r][cq + 2] = v.z; t[r][cq + 3] = v.w;
    }
    __syncthreads();
    {
        int c = tid >> 3, rq = (tid & 7) << 2;
        unsigned u0 = pack2bf(t[rq][c],     t[rq + 1][c]);
        unsigned u1 = pack2bf(t[rq + 2][c], t[rq + 3][c]);
        unsigned* dp = (unsigned*)&dst[(size_t)(c0 + c) * ldd + r0 + rq];
        dp[0] = u0; dp[1] = u1;
    }
}

__global__ void cball_k(const float* __restrict__ bq, const float* __restrict__ bk,
                        const float* __restrict__ bv, float* __restrict__ cb) {
    int idx = blockIdx.x * 256 + threadIdx.x;
    if (idx >= VL * 3 * VD) return;
    int l = idx / (3 * VD), n = idx % (3 * VD);
    int m = n / VD, wi = n % VD;
    const float* p = (m == 0) ? bq : (m == 1) ? bk : bv;
    cb[idx] = p[l * VD + wi];
}

__global__ void cls_k(const float* __restrict__ x, __hip_bfloat16* __restrict__ out) {
    int idx = blockIdx.x * 256 + threadIdx.x;
    if (idx >= VB * VD) return;
    int b = idx / VD, d = idx % VD;
    out[idx] = __float2bfloat16(x[(size_t)b * VS * VD + d]);
}

// ---------------------------------------------------------------------------
// bf16 MFMA GEMM (m97-style 128x128) + XCD swizzle — patch/head only.
// ---------------------------------------------------------------------------
template<int EPI>
__global__ __launch_bounds__(256) void bgemm_k(
    const __hip_bfloat16* __restrict__ A,
    const __hip_bfloat16* __restrict__ BT,
    const float* __restrict__ bias,
    void* __restrict__ Co,
    int M, int K, int ldc, int Ncols)
{
    __shared__ short A_s[128][64];
    __shared__ short B_s[128][64];
    int bx = blockIdx.x, by = blockIdx.y;
    xcd_swz(gridDim.x, gridDim.y, bx, by);
    const int tid = threadIdx.x;
    const int w = tid >> 6, l = tid & 63;
    const int row0 = by * 128, col0 = bx * 128;
    const int wm = (w >> 1) << 6, wn = (w & 1) << 6;
    f32x4 acc[4][4] = {};

    const int lr = l >> 3;
    const int sslot = (l & 7) ^ lr;
    int arow[4], brow[4];
    #pragma unroll
    for (int i = 0; i < 4; i++) {
        int r = (4 * w + i) * 8 + lr;
        arow[i] = min(row0 + r, M - 1);
        brow[i] = min(col0 + r, Ncols - 1);
    }
    for (int k0 = 0; k0 < K; k0 += 64) {
        __syncthreads();
        #pragma unroll
        for (int i = 0; i < 4; i++) {
            int ch = 4 * w + i;
            gload_lds16((const void*)(A + (size_t)arow[i] * K + k0 + (sslot << 3)),
                        (void*)(&A_s[ch * 8][0]));
            gload_lds16((const void*)(BT + (size_t)brow[i] * K + k0 + (sslot << 3)),
                        (void*)(&B_s[ch * 8][0]));
        }
        __syncthreads();
        #pragma unroll
        for (int ks = 0; ks < 2; ks++) {
            const int s16 = (ks << 2) + (l >> 4);
            short8 av[4], bv[4];
            #pragma unroll
            for (int i = 0; i < 4; i++) {
                int ar = wm + i * 16 + (l & 15);
                av[i] = *(const short8*)((const char*)&A_s[ar][0] + ((s16 ^ (ar & 7)) << 4));
                int br = wn + i * 16 + (l & 15);
                bv[i] = *(const short8*)((const char*)&B_s[br][0] + ((s16 ^ (br & 7)) << 4));
            }
            #pragma unroll
            for (int i = 0; i < 4; i++)
                #pragma unroll
                for (int j = 0; j < 4; j++)
                    acc[i][j] = __builtin_amdgcn_mfma_f32_16x16x32_bf16(av[i], bv[j], acc[i][j], 0, 0, 0);
        }
    }
    const int rbase = row0 + wm + ((l >> 4) << 2);
    const int cbase = col0 + wn + (l & 15);
    #pragma unroll
    for (int i = 0; i < 4; i++) {
        #pragma unroll
        for (int q = 0; q < 4; q++) {
            int rr = rbase + i * 16 + q;
            if (rr >= M) continue;
            #pragma unroll
            for (int j = 0; j < 4; j++) {
                int c = cbase + j * 16;
                if (c >= Ncols) continue;
                float v = acc[i][j][q] + bias[c];
                if (EPI == 0) {
                    int orow = rr + rr / VNPAT + 1;
                    ((float*)Co)[(size_t)orow * ldc + c] = v;
                } else if (EPI == 1) {
                    ((__hip_bfloat16*)Co)[(size_t)rr * ldc + c] = __float2bfloat16(v);
                } else if (EPI == 2) {
                    ((float*)Co)[(size_t)rr * ldc + c] += v;
                } else if (EPI == 3) {
                    ((__hip_bfloat16*)Co)[(size_t)rr * ldc + c] = __float2bfloat16(gelu_f(v));
                } else {
                    ((float*)Co)[(size_t)rr * ldc + c] = v;
                }
            }
        }
    }
}

// ---------------------------------------------------------------------------
// bgemm10_k: lean 3-ring 128x128 full-K GEMM with bias + epilogue (champion).
// ---------------------------------------------------------------------------
template<int EPI>
__global__ __launch_bounds__(256) void bgemm10_k(
    const __hip_bfloat16* __restrict__ A,
    const __hip_bfloat16* __restrict__ BT,
    const float* __restrict__ bias,
    __hip_bfloat16* __restrict__ Co,
    int M, int K, int ldc)
{
    __shared__ short SA[3][128][32];
    __shared__ short SB[3][128][32];
    int bx = blockIdx.x, by = blockIdx.y;
    xcd_swz(gridDim.x, gridDim.y, bx, by);

    const int tid = threadIdx.x;
    const int w = tid >> 6, l = tid & 63;
    const int fr = l & 15, g = l >> 4;
    const int row0 = by * 128, col0 = bx * 128;
    const int wm = (w >> 1) << 6, wn = (w & 1) << 6;
    f32x4 acc[4][4] = {};

    const __hip_bfloat16* aS[2]; const __hip_bfloat16* bS[2];
    int doff[2];
    #pragma unroll
    for (int q = 0; q < 2; q++) {
        int idx = tid + (q << 8);
        int r = idx >> 2;
        int s = (idx & 3) ^ ((r >> 1) & 3);
        aS[q] = A  + (size_t)min(row0 + r, M - 1) * K + s * 8;
        bS[q] = BT + (size_t)(col0 + r) * K + s * 8;
        doff[q] = idx << 4;
    }

    #define STG10(ring, t) { const int k0 = (t) << 5;                          \
        gload_lds16(aS[0] + k0, (char*)&SA[ring][0][0] + doff[0]);             \
        gload_lds16(aS[1] + k0, (char*)&SA[ring][0][0] + doff[1]);             \
        gload_lds16(bS[0] + k0, (char*)&SB[ring][0][0] + doff[0]);             \
        gload_lds16(bS[1] + k0, (char*)&SB[ring][0][0] + doff[1]); }

    const int nt = K >> 5;
    STG10(0, 0);
    STG10(1, 1);
    asm volatile("s_waitcnt vmcnt(4)" ::: "memory");
    __builtin_amdgcn_s_barrier();

    for (int t = 0; t < nt; t++) {
        const int ring = t % 3;
        const int rs   = (t + 2) % 3;
        const char* sa = (const char*)&SA[ring][0][0];
        const char* sb = (const char*)&SB[ring][0][0];
        short8 av[4], bv[4];
        #pragma unroll
        for (int i = 0; i < 4; i++) {
            int ar = wm + i * 16 + fr;
            av[i] = *(const short8*)(sa + ar * 64 + ((g ^ ((ar >> 1) & 3)) << 4));
            int br = wn + i * 16 + fr;
            bv[i] = *(const short8*)(sb + br * 64 + ((g ^ ((br >> 1) & 3)) << 4));
        }
        if (t + 2 < nt) STG10(rs, t + 2);
        asm volatile("s_waitcnt lgkmcnt(0)" ::: "memory");
        __builtin_amdgcn_sched_barrier(0);
        __builtin_amdgcn_s_setprio(1);
        #pragma unroll
        for (int i = 0; i < 4; i++)
            #pragma unroll
            for (int j = 0; j < 4; j++)
                acc[i][j] = __builtin_amdgcn_mfma_f32_16x16x32_bf16(av[i], bv[j], acc[i][j], 0, 0, 0);
        __builtin_amdgcn_s_setprio(0);
        if (t + 2 < nt) {
            asm volatile("s_waitcnt vmcnt(4)" ::: "memory");
            __builtin_amdgcn_s_barrier();
        } else if (t + 1 < nt) {
            asm volatile("s_waitcnt vmcnt(0)" ::: "memory");
            __builtin_amdgcn_s_barrier();
        }
    }
    #undef STG10

    const int rbase = row0 + wm + (g << 2);
    const int cbase = col0 + wn + fr;
    #pragma unroll
    for (int i = 0; i < 4; i++) {
        #pragma unroll
        for (int q = 0; q < 4; q++) {
            int rr = rbase + i * 16 + q;
            if (rr >= M) continue;
            #pragma unroll
            for (int j = 0; j < 4; j++) {
                int c = cbase + j * 16;
                float v = acc[i][j][q] + bias[c];
                if (EPI == 3) v = gelu_f(v);
                Co[(size_t)rr * ldc + c] = __float2bfloat16(v);
            }
        }
    }
}

// ---------------------------------------------------------------------------
// bgemm9_k<NSPLIT>: split-K partial GEMM, lean 3-ring 128x128, bf16 partials.
// ---------------------------------------------------------------------------
template<int NSPLIT>
__global__ __launch_bounds__(256) void bgemm9_k(
    const __hip_bfloat16* __restrict__ A,
    const __hip_bfloat16* __restrict__ BT,
    __hip_bfloat16* __restrict__ P,
    int M, int K, int ldc)
{
    __shared__ short SA[3][128][32];
    __shared__ short SB[3][128][32];
    int bx = blockIdx.x, by = blockIdx.y;
    xcd_swz(gridDim.x, gridDim.y, bx, by);
    const int ks = blockIdx.z;
    const int kpart = K / NSPLIT;
    const __hip_bfloat16* Ab  = A  + (size_t)ks * kpart;
    const __hip_bfloat16* BTb = BT + (size_t)ks * kpart;
    __hip_bfloat16* Pb = P + (size_t)ks * TOKD;

    const int tid = threadIdx.x;
    const int w = tid >> 6, l = tid & 63;
    const int fr = l & 15, g = l >> 4;
    const int row0 = by * 128, col0 = bx * 128;
    const int wm = (w >> 1) << 6, wn = (w & 1) << 6;
    f32x4 acc[4][4] = {};

    const __hip_bfloat16* aS[2]; const __hip_bfloat16* bS[2];
    int doff[2];
    #pragma unroll
    for (int q = 0; q < 2; q++) {
        int idx = tid + (q << 8);
        int r = idx >> 2;
        int s = (idx & 3) ^ ((r >> 1) & 3);
        aS[q] = Ab  + (size_t)min(row0 + r, M - 1) * K + s * 8;
        bS[q] = BTb + (size_t)(col0 + r) * K + s * 8;
        doff[q] = idx << 4;
    }

    #define STG9(ring, t) { const int k0 = (t) << 5;                           \
        gload_lds16(aS[0] + k0, (char*)&SA[ring][0][0] + doff[0]);             \
        gload_lds16(aS[1] + k0, (char*)&SA[ring][0][0] + doff[1]);             \
        gload_lds16(bS[0] + k0, (char*)&SB[ring][0][0] + doff[0]);             \
        gload_lds16(bS[1] + k0, (char*)&SB[ring][0][0] + doff[1]); }

    const int nt = kpart >> 5;
    STG9(0, 0);
    STG9(1, 1);
    asm volatile("s_waitcnt vmcnt(4)" ::: "memory");
    __builtin_amdgcn_s_barrier();

    for (int t = 0; t < nt; t++) {
        const int ring = t % 3;
        const int rs   = (t + 2) % 3;
        const char* sa = (const char*)&SA[ring][0][0];
        const char* sb = (const char*)&SB[ring][0][0];
        short8 av[4], bv[4];
        #pragma unroll
        for (int i = 0; i < 4; i++) {
            int ar = wm + i * 16 + fr;
            av[i] = *(const short8*)(sa + ar * 64 + ((g ^ ((ar >> 1) & 3)) << 4));
            int br = wn + i * 16 + fr;
            bv[i] = *(const short8*)(sb + br * 64 + ((g ^ ((br >> 1) & 3)) << 4));
        }
        if (t + 2 < nt) STG9(rs, t + 2);
        asm volatile("s_waitcnt lgkmcnt(0)" ::: "memory");
        __builtin_amdgcn_sched_barrier(0);
        __builtin_amdgcn_s_setprio(1);
        #pragma unroll
        for (int i = 0; i < 4; i++)
            #pragma unroll
            for (int j = 0; j < 4; j++)
                acc[i][j] = __builtin_amdgcn_mfma_f32_16x16x32_bf16(av[i], bv[j], acc[i][j], 0, 0, 0);
        __builtin_amdgcn_s_setprio(0);
        if (t + 2 < nt) {
            asm volatile("s_waitcnt vmcnt(4)" ::: "memory");
            __builtin_amdgcn_s_barrier();
        } else if (t + 1 < nt) {
            asm volatile("s_waitcnt vmcnt(0)" ::: "memory");
            __builtin_amdgcn_s_barrier();
        }
    }
    #undef STG9

    const int rbase = row0 + wm + (g << 2);
    const int cbase = col0 + wn + fr;
    #pragma unroll
    for (int i = 0; i < 4; i++) {
        #pragma unroll
        for (int q = 0; q < 4; q++) {
            int rr = rbase + i * 16 + q;
            if (rr >= M) continue;
            #pragma unroll
            for (int j = 0; j < 4; j++) {
                int c = cbase + j * 16;
                Pb[(size_t)rr * ldc + c] = __float2bfloat16(acc[i][j][q]);
            }
        }
    }
}

// ---------------------------------------------------------------------------
// MFMA attention. Two blocks per (b,h), 256 threads, 4 waves.
// ---------------------------------------------------------------------------
__device__ __forceinline__ int swz_idx(int row, int k) {
    return row * 256 + (((k >> 3) ^ (row & 7)) << 3) + (k & 7);
}

__global__ __launch_bounds__(256) void attn3_k(
    const __hip_bfloat16* __restrict__ qkv, __hip_bfloat16* __restrict__ o)
{
    __shared__ short V_t[64 * 256];
    __shared__ short P_s[4][16 * 256];
    const int half = blockIdx.x;
    const int bh = blockIdx.y;
    const int b = bh / VNH, h = bh % VNH;
    const int tid = threadIdx.x, w = tid >> 6, l = tid & 63;
    const int g = l >> 4, c16 = l & 15;

    const __hip_bfloat16* base = qkv + (size_t)(b * VS) * (3 * VD) + h * VDQ;

    {
        const __hip_bfloat16* vbase = base + 2 * VD;
        int t = tid & 31, e0 = (tid >> 5) * 8;
        #pragma unroll
        for (int it = 0; it < 7; it++) {
            int tt = it * 32 + t;
            if (tt < VS) {
                short8 vv = *(const short8*)(vbase + (size_t)tt * (3 * VD) + e0);
                #pragma unroll
                for (int j = 0; j < 8; j++) V_t[swz_idx(e0 + j, tt)] = vv[j];
            }
        }
        for (int idx = tid; idx < 64 * 27; idx += 256) {
            int e = idx / 27, k = 197 + idx % 27;
            V_t[swz_idx(e, k)] = 0;
        }
    }
    {
        unsigned* p0 = (unsigned*)&P_s[w][swz_idx(c16, 208 + g * 4)];
        p0[0] = 0; p0[1] = 0;
    }
    __syncthreads();

    const int qt_end = half ? 13 : 7;
    for (int qt = 7 * half + w; qt < qt_end; qt += 4) {
        const int q0 = qt * 16;
        int qr = min(q0 + c16, VS - 1);
        const __hip_bfloat16* qp = base + (size_t)qr * (3 * VD) + g * 8;
        short8 qa0 = *(const short8*)(qp);
        short8 qa1 = *(const short8*)(qp + 32);

        f32x4 st[13];
        __builtin_amdgcn_s_setprio(1);
        #pragma unroll
        for (int t = 0; t < 13; t++) {
            int kr = min(t * 16 + c16, VS - 1);
            const __hip_bfloat16* kp = base + VD + (size_t)kr * (3 * VD) + g * 8;
            short8 ka0 = *(const short8*)(kp);
            short8 ka1 = *(const short8*)(kp + 32);
            f32x4 z = {};
            z = __builtin_amdgcn_mfma_f32_16x16x32_bf16(ka0, qa0, z, 0, 0, 0);
            z = __builtin_amdgcn_mfma_f32_16x16x32_bf16(ka1, qa1, z, 0, 0, 0);
            st[t] = z;
        }
        __builtin_amdgcn_s_setprio(0);
        #pragma unroll
        for (int t = 0; t < 13; t++) {
            #pragma unroll
            for (int r = 0; r < 4; r++) {
                float v = st[t][r] * 0.125f;
                if (t == 12 && (4 * g + r) >= 5) v = -3.0e38f;
                st[t][r] = v;
            }
        }
        float m = -3.0e38f;
        #pragma unroll
        for (int t = 0; t < 13; t++)
            #pragma unroll
            for (int r = 0; r < 4; r++) m = fmaxf(m, st[t][r]);
        m = fmaxf(m, __shfl_xor(m, 16));
        m = fmaxf(m, __shfl_xor(m, 32));
        float sum = 0.f;
        #pragma unroll
        for (int t = 0; t < 13; t++)
            #pragma unroll
            for (int r = 0; r < 4; r++) { float e = expf(st[t][r] - m); st[t][r] = e; sum += e; }
        sum += __shfl_xor(sum, 16);
        sum += __shfl_xor(sum, 32);
        float inv = 1.f / sum;
        #pragma unroll
        for (int t = 0; t < 13; t++) {
            int k0 = 16 * t + 4 * g;
            unsigned* pp = (unsigned*)&P_s[w][swz_idx(c16, k0)];
            pp[0] = pack2bf(st[t][0] * inv, st[t][1] * inv);
            pp[1] = pack2bf(st[t][2] * inv, st[t][3] * inv);
        }
        f32x4 acc[4] = {};
        __builtin_amdgcn_s_setprio(1);
        #pragma unroll
        for (int ki = 0; ki < 7; ki++) {
            int k0 = ki * 32 + g * 8;
            short8 pa = *(const short8*)&P_s[w][swz_idx(c16, k0)];
            #pragma unroll
            for (int et = 0; et < 4; et++) {
                short8 vbf = *(const short8*)&V_t[swz_idx(et * 16 + c16, k0)];
                acc[et] = __builtin_amdgcn_mfma_f32_16x16x32_bf16(pa, vbf, acc[et], 0, 0, 0);
            }
        }
        __builtin_amdgcn_s_setprio(0);
        #pragma unroll
        for (int et = 0; et < 4; et++) {
            #pragma unroll
            for (int r = 0; r < 4; r++) {
                int q = q0 + 4 * g + r;
                if (q < VS)
                    o[((size_t)(b * VS) + q) * VD + h * VDQ + et * 16 + c16] =
                        __float2bfloat16(acc[et][r]);
            }
        }
    }
}

// ---------------------------------------------------------------------------
extern "C" void kernel_launch(void* const* d_in, const int* in_sizes, int n_in,
                              void* d_out, int out_size, void* d_ws, size_t ws_size,
                              hipStream_t stream) {
    (void)in_sizes; (void)n_in; (void)out_size; (void)ws_size;
    const float* X       = (const float*)d_in[0];
    const float* patch_W = (const float*)d_in[1];
    const float* patch_b = (const float*)d_in[2];
    const float* cls_tok = (const float*)d_in[3];
    const float* ln1_g   = (const float*)d_in[4];
    const float* ln1_b   = (const float*)d_in[5];
    const float* Wq      = (const float*)d_in[6];
    const float* bq      = (const float*)d_in[7];
    const float* Wk      = (const float*)d_in[8];
    const float* bk      = (const float*)d_in[9];
    const float* Wv      = (const float*)d_in[10];
    const float* bv      = (const float*)d_in[11];
    const float* proj_W  = (const float*)d_in[12];
    const float* proj_b  = (const float*)d_in[13];
    const float* ln2_g   = (const float*)d_in[14];
    const float* ln2_b   = (const float*)d_in[15];
    const float* mlp_W1  = (const float*)d_in[16];
    const float* mlp_b1  = (const float*)d_in[17];
    const float* mlp_W2  = (const float*)d_in[18];
    const float* mlp_b2  = (const float*)d_in[19];
    const float* head_W  = (const float*)d_in[20];
    const float* head_b  = (const float*)d_in[21];

    char* ws = (char*)d_ws;
    float*          x    = (float*)ws;                            // 19.37 MB fp32
    __hip_bfloat16* tb   = (__hip_bfloat16*)(ws + 19365888);      // 9.68 MB bf16
    __hip_bfloat16* big  = (__hip_bfloat16*)(ws + 29048832);      // 38.73 MB
    __hip_bfloat16* wT   = (__hip_bfloat16*)(ws + 67780608);      // 14.16 MB
    float*          cbA  = (float*)(ws + 81936384);               // 110 KB
    __hip_bfloat16* pbuf = (__hip_bfloat16*)(ws + 82046976);      // 38.73 MB (4x TOKD bf16)

    cball_k<<<(VL * 3 * VD + 255) / 256, 256, 0, stream>>>(bq, bk, bv, cbA);

    patchify_k<<<(VB * VNPAT * VP + 255) / 256, 256, 0, stream>>>(X, big);
    {
        dim3 g(VD / 32, VP / 32);
        tpose_k<<<g, 256, 0, stream>>>(patch_W, wT, VP, VD);
    }
    {
        dim3 g(VD / 128, VB * VNPAT / 128);
        bgemm_k<0><<<g, 256, 0, stream>>>(big, wT, patch_b, x, VB * VNPAT, VP, VD, VD);
    }
    pos_cls_k<<<(unsigned)((TOKD + 255) / 256), 256, 0, stream>>>(x, cls_tok);

    const size_t WSZ = (size_t)VNH * VD * VDQ;
    for (int l = 0; l < VL; l++) {
        wprep_k<<<6912, 256, 0, stream>>>(
            Wq + l * WSZ, Wk + l * WSZ, Wv + l * WSZ,
            proj_W + (size_t)l * VD * VD,
            mlp_W1 + (size_t)l * VD * VMLP,
            mlp_W2 + (size_t)l * VMLP * VD, wT);

        if (l == 0)
            layernorm_k<<<VTOK, 256, 0, stream>>>(x, tb, ln1_g, ln1_b);

        {
            // fused QKV GEMM: lean 128² 3-ring, grid 18 x 50
            dim3 g(3 * VD / 128, (VTOK + 127) / 128);
            bgemm10_k<1><<<g, 256, 0, stream>>>(tb, wT, cbA + l * 3 * VD, big,
                                                VTOK, VD, 3 * VD);
        }
        {
            dim3 ga(2, VB * VNH);
            attn3_k<<<ga, 256, 0, stream>>>(big, tb);
        }
        {
            // proj split-K=2 (bf16 partials), then combine + residual + LN2
            dim3 g(VD / 128, (VTOK + 127) / 128, 2);
            bgemm9_k<2><<<g, 256, 0, stream>>>(tb, wT + OFF_PROJ, pbuf, VTOK, VD, VD);
            combineln_k<2, 1><<<VTOK, 192, 0, stream>>>(
                x, pbuf, proj_b + l * VD,
                ln2_g + l * VD, ln2_b + l * VD, tb);
        }
        {
            // MLP1: lean 128² 3-ring + fast-GELU, grid 24 x 50
            dim3 g(VMLP / 128, (VTOK + 127) / 128);
            bgemm10_k<3><<<g, 256, 0, stream>>>(tb, wT + OFF_M1, mlp_b1 + l * VMLP, big,
                                                VTOK, VD, VMLP);
        }
        {
            // MLP2 split-K=4 (bf16 partials), then combine(4) + residual (+ next LN1)
            dim3 g(VD / 128, (VTOK + 127) / 128, 4);
            bgemm9_k<4><<<g, 256, 0, stream>>>(big, wT + OFF_M2, pbuf, VTOK, VMLP, VD);
            if (l + 1 < VL)
                combineln_k<4, 1><<<VTOK, 192, 0, stream>>>(
                    x, pbuf, mlp_b2 + l * VD,
                    ln1_g + (l + 1) * VD, ln1_b + (l + 1) * VD, tb);
            else
                combineln_k<4, 0><<<VTOK, 192, 0, stream>>>(
                    x, pbuf, mlp_b2 + l * VD,
                    nullptr, nullptr, nullptr);
        }
    }
    cls_k<<<(VB * VD + 255) / 256, 256, 0, stream>>>(x, tb);
    {
        dim3 gt((VC + 31) / 32, VD / 32);
        tpose_k<<<gt, 256, 0, stream>>>(head_W, wT, VD, VC);
        dim3 g((VC + 127) / 128, 1);
        bgemm_k<4><<<g, 256, 0, stream>>>(tb, wT, head_b, (float*)d_out,
                                          VB, VD, VC, VC);
    }
}